// Round 1
// baseline (1003.398 us; speedup 1.0000x reference)
//
#include <hip/hip_runtime.h>
#include <hip/hip_bf16.h>

#define NPTS    4096
#define NBATCH  16
#define NPOINT  1024
#define NSAMPLE 32

typedef float v2f __attribute__((ext_vector_type(2)));

// ---------------- DPP helpers (wave reductions without LDS round-trips) ---
#define ROW_SHR1  0x111
#define ROW_SHR2  0x112
#define ROW_SHR4  0x114
#define ROW_SHR8  0x118
#define ROW_BC15  0x142
#define ROW_BC31  0x143

template<int CTRL>
__device__ __forceinline__ unsigned dpp_mov(unsigned v) {
    // bound_ctrl=true: invalid source lanes produce 0 (safe identity: vals >= 0)
    return (unsigned)__builtin_amdgcn_update_dpp(0, (int)v, CTRL, 0xF, 0xF, true);
}
template<int CTRL>
__device__ __forceinline__ float dpp_maxf(float v) {
    unsigned t = dpp_mov<CTRL>(__float_as_uint(v));
    return fmaxf(v, __uint_as_float(t));
}

// ---------------- U precompute role -----------------------------------------
// U[b*4096+p][o] = sum_{c<64} w0[o][3+c] * points[b][c][p]
// One thread per point. Coalesced point loads (lanes = consecutive p),
// weights via wave-uniform scalar loads of contiguous w0 rows.
__device__ void u_role(int g, const float* __restrict__ points,
                       const float* __restrict__ w0, float* __restrict__ U)
{
    const int b = g >> 12, p = g & (NPTS - 1);
    const float* pb = points + (size_t)b * 64 * NPTS + p;
    float in[64];
    #pragma unroll
    for (int c = 0; c < 64; ++c) in[c] = pb[c * NPTS];

    float* ug = U + (size_t)g * 64;
    for (int o4 = 0; o4 < 64; o4 += 4) {
        const float* r0 = w0 + (o4+0)*67 + 3;
        const float* r1 = w0 + (o4+1)*67 + 3;
        const float* r2 = w0 + (o4+2)*67 + 3;
        const float* r3 = w0 + (o4+3)*67 + 3;
        float a0 = 0.f, a1 = 0.f, a2 = 0.f, a3 = 0.f;
        #pragma unroll
        for (int c = 0; c < 64; ++c) {
            const float x = in[c];
            a0 = fmaf(r0[c], x, a0);
            a1 = fmaf(r1[c], x, a1);
            a2 = fmaf(r2[c], x, a2);
            a3 = fmaf(r3[c], x, a3);
        }
        *(float4*)(ug + o4) = make_float4(a0, a1, a2, a3);
    }
}

// ---------------- setup role -------------------------------------------------
// w0 first-3-rows transposed, w1 transposed to k-major, BN folded scale/shift.
__device__ void setup_role(
    const float* __restrict__ w0, const float* __restrict__ b0,
    const float* __restrict__ g0, const float* __restrict__ be0,
    const float* __restrict__ m0, const float* __restrict__ v0,
    const float* __restrict__ w1, const float* __restrict__ b1,
    const float* __restrict__ g1, const float* __restrict__ be1,
    const float* __restrict__ m1, const float* __restrict__ v1,
    const float* __restrict__ b2, const float* __restrict__ g2,
    const float* __restrict__ be2, const float* __restrict__ m2,
    const float* __restrict__ v2, float* __restrict__ wp)
{
    const int t = threadIdx.x;
    for (int i = t; i < 3*64; i += 256) {
        int k = i >> 6, o = i & 63;
        wp[i] = w0[o*67 + k];                      // w0t3 [3][64]
    }
    for (int i = t; i < 64*64; i += 256) {
        int o = i >> 6, k = i & 63;
        wp[192 + k*64 + o] = w1[i];                // w1t [64][64]
    }
    if (t < 64) {
        float s0 = g0[t] / sqrtf(v0[t] + 1e-5f);
        wp[4288 + t] = s0;
        wp[4352 + t] = (b0[t] - m0[t]) * s0 + be0[t];
        float s1 = g1[t] / sqrtf(v1[t] + 1e-5f);
        wp[4416 + t] = s1;
        wp[4480 + t] = (b1[t] - m1[t]) * s1 + be1[t];
    }
    if (t < 128) {
        float s2 = g2[t] / sqrtf(v2[t] + 1e-5f);
        wp[4544 + t] = s2;
        wp[4672 + t] = (b2[t] - m2[t]) * s2 + be2[t];
    }
}

// ---------------- fused: FPS (blocks 0-15) + U (16-271) + setup (272) --------
// FPS: one block per batch, 256 threads (4 waves), 16 CONTIGUOUS points per
// thread so min-lane == min-index on ties. Exact f32 (contract off, packed
// v_pk f32 math = identical IEEE rounding). Argmax: per-thread strict-> first
// max -> 6-step DPP wave max -> ballot -> first lane -> readlane(idx).
// Cross-wave: each wave writes {u64 key, winning float4 coords} to dbuf slots;
// after one barrier every lane selects the max of 4 slots directly (coords in
// slots removes the dependent post-barrier P[f] LDS read).
__global__ __launch_bounds__(256) void fps_fused_kernel(
    const float* __restrict__ xyz, const float* __restrict__ points,
    const float* __restrict__ w0, const float* __restrict__ b0,
    const float* __restrict__ g0, const float* __restrict__ be0,
    const float* __restrict__ m0, const float* __restrict__ v0,
    const float* __restrict__ w1, const float* __restrict__ b1,
    const float* __restrict__ g1, const float* __restrict__ be1,
    const float* __restrict__ m1, const float* __restrict__ v1,
    const float* __restrict__ b2, const float* __restrict__ g2,
    const float* __restrict__ be2, const float* __restrict__ m2,
    const float* __restrict__ v2,
    float* __restrict__ newxyz, float* __restrict__ U, float* __restrict__ wp)
{
    #pragma clang fp contract(off)
    if (blockIdx.x >= 16) {
        if (blockIdx.x < 272) {
            u_role((blockIdx.x - 16) * 256 + threadIdx.x, points, w0, U);
        } else {
            setup_role(w0,b0,g0,be0,m0,v0, w1,b1,g1,be1,m1,v1,
                       b2,g2,be2,m2,v2, wp);
        }
        return;
    }

    const int b    = blockIdx.x;
    const int tid  = threadIdx.x;
    const int lane = tid & 63;
    const int w    = tid >> 6;
    const float* xb = xyz + (size_t)b * 3 * NPTS;

    __shared__ float4 P[NPTS];                       // x,y,z,pad (64 KiB)
    __shared__ unsigned long long slotk[2][4];
    __shared__ float4 slotc[2][4];

    v2f px2[8], py2[8], pz2[8], dist2[8];
    #pragma unroll
    for (int q = 0; q < 4; ++q) {
        const int n4 = tid * 16 + q * 4;
        float4 xs = *(const float4*)(xb + n4);
        float4 ys = *(const float4*)(xb + NPTS + n4);
        float4 zs = *(const float4*)(xb + 2*NPTS + n4);
        px2[2*q+0] = (v2f){xs.x, xs.y}; px2[2*q+1] = (v2f){xs.z, xs.w};
        py2[2*q+0] = (v2f){ys.x, ys.y}; py2[2*q+1] = (v2f){ys.z, ys.w};
        pz2[2*q+0] = (v2f){zs.x, zs.y}; pz2[2*q+1] = (v2f){zs.z, zs.w};
        P[n4+0] = make_float4(xs.x, ys.x, zs.x, 0.f);
        P[n4+1] = make_float4(xs.y, ys.y, zs.y, 0.f);
        P[n4+2] = make_float4(xs.z, ys.z, zs.z, 0.f);
        P[n4+3] = make_float4(xs.w, ys.w, zs.w, 0.f);
    }
    #pragma unroll
    for (int j = 0; j < 8; ++j) dist2[j] = (v2f){1e10f, 1e10f};
    __syncthreads();

    float4 c0 = P[0];
    float cx = c0.x, cy = c0.y, cz = c0.z;
    if (tid == 0) {
        newxyz[b*3*NPOINT + 0]        = cx;
        newxyz[b*3*NPOINT + NPOINT]   = cy;
        newxyz[b*3*NPOINT + 2*NPOINT] = cz;
    }

    for (int i = 1; i < NPOINT; ++i) {
        const int s = i & 1;
        const v2f cx2 = (v2f){cx, cx};
        const v2f cy2 = (v2f){cy, cy};
        const v2f cz2 = (v2f){cz, cz};
        float bv = -1.0f; int bj = 0;
        #pragma unroll
        for (int j2 = 0; j2 < 8; ++j2) {
            v2f dx = px2[j2] - cx2;
            v2f dy = py2[j2] - cy2;
            v2f dz = pz2[j2] - cz2;
            v2f xx = dx*dx, yy = dy*dy, zz = dz*dz;
            v2f dd = (xx + yy) + zz;       // same assoc as np: (x2+y2)+z2
            v2f nd;
            nd.x = fminf(dist2[j2].x, dd.x);
            nd.y = fminf(dist2[j2].y, dd.y);
            dist2[j2] = nd;
            if (nd.x > bv) { bv = nd.x; bj = 2*j2; }     // strict >: first max
            if (nd.y > bv) { bv = nd.y; bj = 2*j2+1; }
        }
        const int myidx = (tid << 4) | bj;

        // wave max of bv (values >= 0 so bound_ctrl-0 is identity-safe)
        float wv = bv;
        wv = dpp_maxf<ROW_SHR1>(wv);
        wv = dpp_maxf<ROW_SHR2>(wv);
        wv = dpp_maxf<ROW_SHR4>(wv);
        wv = dpp_maxf<ROW_SHR8>(wv);
        wv = dpp_maxf<ROW_BC15>(wv);
        wv = dpp_maxf<ROW_BC31>(wv);                 // lane 63 = wave max
        float wmax = __uint_as_float(
            (unsigned)__builtin_amdgcn_readlane((int)__float_as_uint(wv), 63));
        unsigned long long mask = __ballot(bv == wmax);
        int L = (int)__builtin_ctzll(mask);          // first lane = min idx
        int widx = __builtin_amdgcn_readlane(myidx, L);

        float4 cand = P[widx];                       // uniform-addr broadcast
        if (lane == 0) {
            slotk[s][w] = ((unsigned long long)__float_as_uint(wmax) << 32) |
                          (unsigned long long)(unsigned)(~widx);
            slotc[s][w] = cand;
        }
        __syncthreads();

        // every lane: pick max of 4 slots (keys are distinct by construction)
        unsigned long long k0 = slotk[s][0], k1 = slotk[s][1];
        unsigned long long k2 = slotk[s][2], k3 = slotk[s][3];
        float4 s0 = slotc[s][0], s1 = slotc[s][1];
        float4 s2 = slotc[s][2], s3 = slotc[s][3];
        bool b01 = k1 > k0;
        unsigned long long ka = b01 ? k1 : k0;
        float ax = b01 ? s1.x : s0.x, ay = b01 ? s1.y : s0.y, az = b01 ? s1.z : s0.z;
        bool b23 = k3 > k2;
        unsigned long long kb = b23 ? k3 : k2;
        float bx = b23 ? s3.x : s2.x, by = b23 ? s3.y : s2.y, bz = b23 ? s3.z : s2.z;
        bool ab = kb > ka;
        cx = ab ? bx : ax; cy = ab ? by : ay; cz = ab ? bz : az;

        if (tid == 0) {
            newxyz[b*3*NPOINT + i]            = cx;
            newxyz[b*3*NPOINT + NPOINT + i]   = cy;
            newxyz[b*3*NPOINT + 2*NPOINT + i] = cz;
        }
    }
}

// ---------------- K2: query_ball_point ---------------------------------------
// One wave per centroid: ordered scan of all 4096 points; ballot + prefix
// popcount emits the first 32 in-radius indices in ascending order; pad with
// the first found index. Exact f32 distances (no fma).
__global__ __launch_bounds__(256) void ball_kernel(
    const float* __restrict__ xyz, const float* __restrict__ newxyz,
    int* __restrict__ ball_idx)
{
    const int gid  = blockIdx.x * 256 + threadIdx.x;
    const int wid  = gid >> 6;                 // 0 .. 16383
    const int lane = threadIdx.x & 63;
    const int b    = wid >> 10;
    const int m    = wid & (NPOINT - 1);
    const float r2 = (float)(0.2 * 0.2);

    const float* xb = xyz + (size_t)b * 3 * NPTS;
    const float cx = newxyz[b*3*NPOINT + m];
    const float cy = newxyz[b*3*NPOINT + NPOINT + m];
    const float cz = newxyz[b*3*NPOINT + 2*NPOINT + m];
    int* out = ball_idx + (size_t)wid * NSAMPLE;

    int base = 0, first = 0;
    for (int c0 = 0; c0 < NPTS; c0 += 64) {
        const int n = c0 + lane;
        float dx = xb[n] - cx, dy = xb[NPTS+n] - cy, dz = xb[2*NPTS+n] - cz;
        float d = __fadd_rn(__fadd_rn(__fmul_rn(dx,dx), __fmul_rn(dy,dy)),
                            __fmul_rn(dz,dz));
        bool inb = (d <= r2);
        unsigned long long mask = __ballot(inb);
        if (base == 0 && mask != 0ull) first = c0 + (int)__builtin_ctzll(mask);
        int pos = base + __popcll(mask & ((1ull << lane) - 1ull));
        if (inb && pos < NSAMPLE) out[pos] = n;
        base += __popcll(mask);
        if (base >= NSAMPLE) break;
    }
    if (lane < NSAMPLE && lane >= base) out[lane] = first;  // pad with first
}

// ---------------- K3: gather + 3-layer MLP + maxpool -------------------------
// One lane per (centroid, sample) column. Layer-0 point-feature part comes
// precomputed from U (16 contiguous float4 loads instead of 64 strided dword
// gathers + 4096 FMAs); only the 3 norm channels are applied here. All
// activations in VGPRs; weights via wave-uniform scalar loads; max over 32
// samples with a 5-step DPP chain; lanes 31/63 store.
__global__ __launch_bounds__(256) void mlp_kernel(
    const float* __restrict__ xyz, const float* __restrict__ newxyz,
    const int* __restrict__ ball_idx, const float* __restrict__ U,
    const float* __restrict__ wp, const float* __restrict__ w2,
    float* __restrict__ out)
{
    const int col = blockIdx.x * 256 + threadIdx.x;   // 0 .. 524287
    const int m   = (col >> 5) & (NPOINT - 1);
    const int b   = col >> 15;
    const int p   = ball_idx[col];

    const float* xb = xyz + (size_t)b * 3 * NPTS;
    const float n0 = xb[p]          - newxyz[b*3*NPOINT + m];
    const float n1 = xb[NPTS + p]   - newxyz[b*3*NPOINT + NPOINT + m];
    const float n2 = xb[2*NPTS + p] - newxyz[b*3*NPOINT + 2*NPOINT + m];

    const float* w0t3 = wp;            // [3][64]
    const float* w1t  = wp + 192;      // [64][64]
    const float* sc0  = wp + 4288;
    const float* sh0  = wp + 4352;
    const float* sc1  = wp + 4416;
    const float* sh1  = wp + 4480;
    const float* sc2  = wp + 4544;
    const float* sh2  = wp + 4672;

    // h = U[b,p,:] (precomputed point-feature part of layer 0)
    float h[64];
    const float4* Up = (const float4*)(U + ((size_t)((b << 12) | p)) * 64);
    #pragma unroll
    for (int q = 0; q < 16; ++q) {
        float4 u = Up[q];
        h[4*q+0] = u.x; h[4*q+1] = u.y; h[4*q+2] = u.z; h[4*q+3] = u.w;
    }
    #pragma unroll
    for (int o = 0; o < 64; ++o) h[o] = fmaf(w0t3[o],       n0, h[o]);
    #pragma unroll
    for (int o = 0; o < 64; ++o) h[o] = fmaf(w0t3[64 + o],  n1, h[o]);
    #pragma unroll
    for (int o = 0; o < 64; ++o) h[o] = fmaf(w0t3[128 + o], n2, h[o]);
    #pragma unroll
    for (int o = 0; o < 64; ++o)
        h[o] = fmaxf(fmaf(h[o], sc0[o], sh0[o]), 0.0f);

    float g[64];
    #pragma unroll
    for (int o = 0; o < 64; ++o) g[o] = 0.0f;
    #pragma unroll
    for (int k = 0; k < 64; ++k) {
        const float x = h[k];
        #pragma unroll
        for (int o = 0; o < 64; ++o) g[o] = fmaf(w1t[k*64 + o], x, g[o]);
    }
    #pragma unroll
    for (int o = 0; o < 64; ++o)
        g[o] = fmaxf(fmaf(g[o], sc1[o], sh1[o]), 0.0f);

    float* outb = out + (size_t)b * 128 * NPOINT + m;
    #pragma unroll 2
    for (int o = 0; o < 128; ++o) {
        float acc = 0.0f;
        const float* wr = w2 + o * 64;
        #pragma unroll
        for (int k = 0; k < 64; ++k) acc = fmaf(wr[k], g[k], acc);
        acc = fmaxf(fmaf(acc, sc2[o], sh2[o]), 0.0f);
        acc = dpp_maxf<ROW_SHR1>(acc);
        acc = dpp_maxf<ROW_SHR2>(acc);
        acc = dpp_maxf<ROW_SHR4>(acc);
        acc = dpp_maxf<ROW_SHR8>(acc);
        acc = dpp_maxf<ROW_BC15>(acc);   // lane31 = max(0..31), lane63 = max(32..63)
        if ((threadIdx.x & 31) == 31) outb[o * NPOINT] = acc;
    }
}

// ---------------- launch ------------------------------------------------------
extern "C" void kernel_launch(void* const* d_in, const int* in_sizes, int n_in,
                              void* d_out, int out_size, void* d_ws, size_t ws_size,
                              hipStream_t stream)
{
    const float* xyz    = (const float*)d_in[0];
    const float* points = (const float*)d_in[1];
    const float* w0  = (const float*)d_in[2];
    const float* b0  = (const float*)d_in[3];
    const float* g0  = (const float*)d_in[4];
    const float* be0 = (const float*)d_in[5];
    const float* m0  = (const float*)d_in[6];
    const float* v0  = (const float*)d_in[7];
    const float* w1  = (const float*)d_in[8];
    const float* b1  = (const float*)d_in[9];
    const float* g1  = (const float*)d_in[10];
    const float* be1 = (const float*)d_in[11];
    const float* m1  = (const float*)d_in[12];
    const float* v1  = (const float*)d_in[13];
    const float* w2  = (const float*)d_in[14];
    const float* b2  = (const float*)d_in[15];
    const float* g2  = (const float*)d_in[16];
    const float* be2 = (const float*)d_in[17];
    const float* m2  = (const float*)d_in[18];
    const float* v2  = (const float*)d_in[19];

    float* out0 = (float*)d_out;                       // (16,3,1024)
    float* out1 = out0 + NBATCH * 3 * NPOINT;          // (16,128,1024)

    // workspace layout: U (16.78 MB) | ball (2 MB) | wp (~19 KB)
    float* U    = (float*)d_ws;
    int*   ball = (int*)((char*)d_ws + (size_t)NBATCH*NPTS*64*sizeof(float));
    float* wp   = (float*)((char*)ball + (size_t)NBATCH*NPOINT*NSAMPLE*sizeof(int));

    // blocks 0-15: FPS | 16-271: U precompute | 272: weight prep.
    // FPS holds 16 CUs for ~350 us; U+setup run on the other 240 CUs for free.
    hipLaunchKernelGGL(fps_fused_kernel, dim3(273), dim3(256), 0, stream,
                       xyz, points, w0,b0,g0,be0,m0,v0, w1,b1,g1,be1,m1,v1,
                       b2,g2,be2,m2,v2, out0, U, wp);
    hipLaunchKernelGGL(ball_kernel, dim3(NBATCH*NPOINT/4), dim3(256), 0, stream,
                       xyz, out0, ball);
    hipLaunchKernelGGL(mlp_kernel,  dim3(NBATCH*NPOINT*NSAMPLE/256), dim3(256), 0, stream,
                       xyz, out0, ball, U, wp, w2, out1);
}